// Round 1
// baseline (230.697 us; speedup 1.0000x reference)
//
#include <hip/hip_runtime.h>
#include <hip/hip_fp16.h>
#include <cmath>

// ---------------- types ----------------
typedef _Float16 half8 __attribute__((ext_vector_type(8)));
typedef _Float16 half4_t __attribute__((ext_vector_type(4)));
typedef float f32x4 __attribute__((ext_vector_type(4)));

#define LDIM 4096
#define DDIM 1024
#define NSTATE 16
#define NCHUNK 128
#define CLEN 32   // LDIM / NCHUNK

// ---------------- K0: transpose W_delta (K x N f32) -> Wt (N x K f16) ----------------
__global__ __launch_bounds__(256) void k_transpose(const float* __restrict__ W,
                                                   _Float16* __restrict__ Wt) {
  __shared__ float tile[64][65];
  const int n0 = blockIdx.x * 64, k0 = blockIdx.y * 64;
  const int t = threadIdx.x;
#pragma unroll
  for (int i = 0; i < 16; ++i) {
    int idx = t + i * 256;
    int kk = idx >> 6, nn = idx & 63;
    tile[kk][nn] = W[(size_t)(k0 + kk) * DDIM + n0 + nn];
  }
  __syncthreads();
#pragma unroll
  for (int i = 0; i < 16; ++i) {
    int idx = t + i * 256;
    int nn = idx >> 6, kk = idx & 63;
    Wt[(size_t)(n0 + nn) * DDIM + k0 + kk] = (_Float16)tile[kk][nn];
  }
}

// ---------------- K1: RMSNorm -> xn (f32) and xn (f16) ----------------
__global__ __launch_bounds__(256) void k_rmsnorm(const float* __restrict__ x,
                                                 const float* __restrict__ nw,
                                                 float* __restrict__ xnf,
                                                 _Float16* __restrict__ xnh) {
  const int l = blockIdx.x, t = threadIdx.x;
  float4 v = ((const float4*)(x + (size_t)l * DDIM))[t];
  float ss = v.x * v.x + v.y * v.y + v.z * v.z + v.w * v.w;
#pragma unroll
  for (int off = 32; off; off >>= 1) ss += __shfl_xor(ss, off, 64);
  __shared__ float sred[4];
  if ((t & 63) == 0) sred[t >> 6] = ss;
  __syncthreads();
  float tot = sred[0] + sred[1] + sred[2] + sred[3];
  float r = rsqrtf(tot * (1.0f / (float)DDIM) + 1e-6f);
  float4 wv = ((const float4*)nw)[t];
  float4 o;
  o.x = v.x * wv.x * r; o.y = v.y * wv.y * r;
  o.z = v.z * wv.z * r; o.w = v.w * wv.w * r;
  ((float4*)(xnf + (size_t)l * DDIM))[t] = o;
  half4_t h;
  h[0] = (_Float16)o.x; h[1] = (_Float16)o.y; h[2] = (_Float16)o.z; h[3] = (_Float16)o.w;
  ((half4_t*)(xnh + (size_t)l * DDIM))[t] = h;
}

// ---------------- K2: delta GEMM (f16 MFMA) + softplus + soft_clamp; writes dx={sqrt(delta), xn} ----------------
// A = xn_h (M=4096 x K=1024), B = Wt_h (N=1024 x K=1024, i.e. W^T), C[l,d] = sum_k A[l,k]*W[k,d]
__global__ __launch_bounds__(256) void k_gemm_delta(const _Float16* __restrict__ Ah,
                                                    const _Float16* __restrict__ Bh,
                                                    const float* __restrict__ xnf,
                                                    const float* __restrict__ b_delta,
                                                    float2* __restrict__ dxo) {
  __shared__ __align__(16) _Float16 As[128 * 32];
  __shared__ __align__(16) _Float16 Bs[128 * 32];
  const int t = threadIdx.x;
  const int w = t >> 6, lane = t & 63;
  const int quad = lane >> 4, l16 = lane & 15;
  const int wr = w >> 1, wc = w & 1;
  const int tileM = blockIdx.y * 128, tileN = blockIdx.x * 128;
  const int K = DDIM;

  // staging: thread t owns 16B segs {t, t+256} of each 8KB tile; seg s -> row s>>2, kseg s&3
  const int sA0 = t, sA1 = t + 256;
  const half8* gA0 = (const half8*)(Ah + (size_t)(tileM + (sA0 >> 2)) * K + (sA0 & 3) * 8);
  const half8* gA1 = (const half8*)(Ah + (size_t)(tileM + (sA1 >> 2)) * K + (sA1 & 3) * 8);
  const half8* gB0 = (const half8*)(Bh + (size_t)(tileN + (sA0 >> 2)) * K + (sA0 & 3) * 8);
  const half8* gB1 = (const half8*)(Bh + (size_t)(tileN + (sA1 >> 2)) * K + (sA1 & 3) * 8);
  half8* lA0 = (half8*)As + sA0;
  half8* lA1 = (half8*)As + sA1;
  half8* lB0 = (half8*)Bs + sA0;
  half8* lB1 = (half8*)Bs + sA1;

  f32x4 acc[4][4];
#pragma unroll
  for (int i = 0; i < 4; ++i)
#pragma unroll
    for (int j = 0; j < 4; ++j) acc[i][j] = (f32x4){0.f, 0.f, 0.f, 0.f};

  half8 rA0 = *gA0, rA1 = *gA1, rB0 = *gB0, rB1 = *gB1;
  gA0 += 4; gA1 += 4; gB0 += 4; gB1 += 4;

  for (int kt = 0; kt < K / 32; ++kt) {
    __syncthreads();
    *lA0 = rA0; *lA1 = rA1; *lB0 = rB0; *lB1 = rB1;
    __syncthreads();
    if (kt < K / 32 - 1) {
      rA0 = *gA0; rA1 = *gA1; rB0 = *gB0; rB1 = *gB1;
      gA0 += 4; gA1 += 4; gB0 += 4; gB1 += 4;
    }
    half8 af[4], bf[4];
#pragma unroll
    for (int i = 0; i < 4; ++i)
      af[i] = *(const half8*)(As + (wr * 64 + i * 16 + l16) * 32 + quad * 8);
#pragma unroll
    for (int j = 0; j < 4; ++j)
      bf[j] = *(const half8*)(Bs + (wc * 64 + j * 16 + l16) * 32 + quad * 8);
#pragma unroll
    for (int i = 0; i < 4; ++i)
#pragma unroll
      for (int j = 0; j < 4; ++j)
        acc[i][j] = __builtin_amdgcn_mfma_f32_16x16x32_f16(af[i], bf[j], acc[i][j], 0, 0, 0);
  }

  // epilogue: delta = soft_clamp(softplus(z + b)); store {sqrt(delta), xn_f32}
  const float cC = 5.00005f, cH = 4.99995f, invH = 1.0f / 4.99995f;
  float bdl[4];
#pragma unroll
  for (int j = 0; j < 4; ++j) bdl[j] = b_delta[tileN + wc * 64 + j * 16 + l16];
#pragma unroll
  for (int i = 0; i < 4; ++i) {
#pragma unroll
    for (int r = 0; r < 4; ++r) {
      int row = tileM + wr * 64 + i * 16 + quad * 4 + r;
#pragma unroll
      for (int j = 0; j < 4; ++j) {
        int col = tileN + wc * 64 + j * 16 + l16;
        float z = acc[i][j][r] + bdl[j];
        float sp = fmaxf(z, 0.f) + log1pf(__expf(-fabsf(z)));   // stable softplus
        float dt = cC + cH * tanhf((sp - cC) * invH);           // soft clamp to [1e-4, 10]
        float xv = xnf[(size_t)row * DDIM + col];
        dxo[(size_t)row * DDIM + col] = make_float2(sqrtf(dt), xv);
      }
    }
  }
}

// ---------------- K3: Bp = xn@W_B, C = xn@W_C -> bpc[l][n] = {Bp, C} ----------------
__global__ __launch_bounds__(256) void k_bpc(const float* __restrict__ xnf,
                                             const float* __restrict__ WB,
                                             const float* __restrict__ WC,
                                             float* __restrict__ bpcf) {
  const int l = blockIdx.x, t = threadIdx.x;
  const int no = t & 31, p = t >> 5;          // 32 outputs x 8 k-partitions
  const float* W = (no < 16) ? WB : WC;
  const int n = no & 15;
  const float* xr = xnf + (size_t)l * DDIM + p * 128;
  float s = 0.f;
#pragma unroll 4
  for (int k = 0; k < 128; ++k) s = fmaf(xr[k], W[(p * 128 + k) * NSTATE + n], s);
  __shared__ float sh[256];
  sh[t] = s;
  __syncthreads();
  if (t < 32) {
    float tot = 0.f;
#pragma unroll
    for (int q = 0; q < 8; ++q) tot += sh[no + 32 * q];
    bpcf[(size_t)l * 32 + n * 2 + (no >> 4)] = tot;   // float2 {Bp, C} per (l,n)
  }
}

// ---------------- scan math helper ----------------
// hd = delta*0.5*A (<=0), ab = (1+hd)/(1-hd), bx = sqrt(delta)*Bp*xn/(1-hd)

// K4a: per-chunk local scan -> {prod A_bar, h_end}
__global__ __launch_bounds__(256) void k_scan1(const float2* __restrict__ dx,
                                               const float2* __restrict__ bpc,
                                               const float* __restrict__ A_log,
                                               float2* __restrict__ Ph) {
  const int d = blockIdx.x * 256 + threadIdx.x;
  const int c = blockIdx.y;
  float halfA[NSTATE], h[NSTATE], P[NSTATE];
#pragma unroll
  for (int n = 0; n < NSTATE; ++n) {
    halfA[n] = -0.5f * __expf(A_log[d * NSTATE + n]);
    h[n] = 0.f; P[n] = 1.f;
  }
  const float2* dxr = dx + (size_t)c * CLEN * DDIM + d;
  const float2* br = bpc + (size_t)c * CLEN * NSTATE;
#pragma unroll 2
  for (int i = 0; i < CLEN; ++i) {
    float2 sx = dxr[(size_t)i * DDIM];
    float dsq = sx.x * sx.x;        // delta
    float sdx = sx.x * sx.y;        // sqrt(delta)*xn
#pragma unroll
    for (int n = 0; n < NSTATE; ++n) {
      float2 bc = br[i * NSTATE + n];     // block-uniform -> scalar loads
      float hd = dsq * halfA[n];
      float di = __builtin_amdgcn_rcpf(1.0f - hd);  // 1-hd >= 1 always
      float ab = fmaf(hd, di, di);
      h[n] = fmaf(ab, h[n], sdx * bc.x * di);
      P[n] *= ab;
    }
  }
#pragma unroll
  for (int n = 0; n < NSTATE; ++n)
    Ph[((size_t)c * NSTATE + n) * DDIM + d] = make_float2(P[n], h[n]);
}

// K4c: sequential combine across chunks -> chunk-entry states
__global__ __launch_bounds__(256) void k_comb(const float2* __restrict__ Ph,
                                              float* __restrict__ Hinit) {
  const int g = blockIdx.x * 256 + threadIdx.x;   // g = n*1024 + d, 16384 total
  float H = 0.f;
  for (int c = 0; c < NCHUNK; ++c) {
    float2 ph = Ph[(size_t)c * (DDIM * NSTATE) + g];
    Hinit[(size_t)c * (DDIM * NSTATE) + g] = H;
    H = fmaf(ph.x, H, ph.y);
  }
}

// K4b: re-run chunk scans with correct h0, emit y
__global__ __launch_bounds__(256) void k_scan2(const float2* __restrict__ dx,
                                               const float2* __restrict__ bpc,
                                               const float* __restrict__ A_log,
                                               const float* __restrict__ Hinit,
                                               const float* __restrict__ Dskip,
                                               float* __restrict__ y) {
  const int d = blockIdx.x * 256 + threadIdx.x;
  const int c = blockIdx.y;
  float halfA[NSTATE], h[NSTATE];
#pragma unroll
  for (int n = 0; n < NSTATE; ++n) {
    halfA[n] = -0.5f * __expf(A_log[d * NSTATE + n]);
    h[n] = Hinit[(size_t)c * (DDIM * NSTATE) + n * DDIM + d];
  }
  const float dsk = Dskip[d];
  const float2* dxr = dx + (size_t)c * CLEN * DDIM + d;
  const float2* br = bpc + (size_t)c * CLEN * NSTATE;
  float* yr = y + (size_t)c * CLEN * DDIM + d;
#pragma unroll 2
  for (int i = 0; i < CLEN; ++i) {
    float2 sx = dxr[(size_t)i * DDIM];
    float dsq = sx.x * sx.x;
    float sdx = sx.x * sx.y;
    float acc = dsk * sx.y;
#pragma unroll
    for (int n = 0; n < NSTATE; ++n) {
      float2 bc = br[i * NSTATE + n];
      float hd = dsq * halfA[n];
      float di = __builtin_amdgcn_rcpf(1.0f - hd);
      float ab = fmaf(hd, di, di);
      h[n] = fmaf(ab, h[n], sdx * bc.x * di);
      acc = fmaf(bc.y, h[n], acc);
    }
    yr[(size_t)i * DDIM] = acc;
  }
}

// ---------------- launch ----------------
extern "C" void kernel_launch(void* const* d_in, const int* in_sizes, int n_in,
                              void* d_out, int out_size, void* d_ws, size_t ws_size,
                              hipStream_t stream) {
  const float* x       = (const float*)d_in[0];
  const float* A_log   = (const float*)d_in[1];
  const float* W_delta = (const float*)d_in[2];
  const float* b_delta = (const float*)d_in[3];
  const float* W_B     = (const float*)d_in[4];
  const float* W_C     = (const float*)d_in[5];
  const float* D_skip  = (const float*)d_in[6];
  const float* norm_w  = (const float*)d_in[7];
  float* y = (float*)d_out;

  char* ws = (char*)d_ws;
  const size_t MB = 1024 * 1024;
  float*    xnf = (float*)(ws);                 // 16 MB  xn f32
  _Float16* xnh = (_Float16*)(ws + 16 * MB);    //  8 MB  xn f16
  _Float16* Wth = (_Float16*)(ws + 24 * MB);    //  2 MB  W_delta^T f16
  float2*   dx  = (float2*)(ws + 26 * MB);      // 32 MB  {sqrt(delta), xn}
  float2*   bpc = (float2*)(ws + 58 * MB);      // .5 MB  {Bp, C}
  float2*   Ph  = (float2*)(ws + 59 * MB);      // 16 MB  {prodA, h_end}
  float*    Hin = (float*)(ws + 75 * MB);       //  8 MB  chunk-entry states
  (void)ws_size; (void)in_sizes; (void)n_in; (void)out_size;

  hipLaunchKernelGGL(k_transpose, dim3(16, 16), dim3(256), 0, stream, W_delta, Wth);
  hipLaunchKernelGGL(k_rmsnorm, dim3(LDIM), dim3(256), 0, stream, x, norm_w, xnf, xnh);
  hipLaunchKernelGGL(k_gemm_delta, dim3(DDIM / 128, LDIM / 128), dim3(256), 0, stream,
                     xnh, Wth, xnf, b_delta, dx);
  hipLaunchKernelGGL(k_bpc, dim3(LDIM), dim3(256), 0, stream, xnf, W_B, W_C, (float*)bpc);
  hipLaunchKernelGGL(k_scan1, dim3(DDIM / 256, NCHUNK), dim3(256), 0, stream, dx, bpc, A_log, Ph);
  hipLaunchKernelGGL(k_comb, dim3(64), dim3(256), 0, stream, Ph, Hin);
  hipLaunchKernelGGL(k_scan2, dim3(DDIM / 256, NCHUNK), dim3(256), 0, stream,
                     dx, bpc, A_log, Hin, D_skip, y);
}

// Round 2
// 211.135 us; speedup vs baseline: 1.0926x; 1.0926x over previous
//
#include <hip/hip_runtime.h>
#include <hip/hip_fp16.h>
#include <cmath>

// ---------------- types ----------------
typedef _Float16 half8 __attribute__((ext_vector_type(8)));
typedef _Float16 half4_t __attribute__((ext_vector_type(4)));
typedef float f32x4 __attribute__((ext_vector_type(4)));

#define LDIM 4096
#define DDIM 1024
#define NSTATE 16
#define NCHUNK 128
#define CLEN 32   // LDIM / NCHUNK
#define LDSPAD 40 // padded row stride in halves (80B, 16B-aligned)

// ---------------- K0: transpose W_delta (K x N f32) -> Wt (N x K f16) ----------------
__global__ __launch_bounds__(256) void k_transpose(const float* __restrict__ W,
                                                   _Float16* __restrict__ Wt) {
  __shared__ float tile[64][65];
  const int n0 = blockIdx.x * 64, k0 = blockIdx.y * 64;
  const int t = threadIdx.x;
#pragma unroll
  for (int i = 0; i < 16; ++i) {
    int idx = t + i * 256;
    int kk = idx >> 6, nn = idx & 63;
    tile[kk][nn] = W[(size_t)(k0 + kk) * DDIM + n0 + nn];
  }
  __syncthreads();
#pragma unroll
  for (int i = 0; i < 16; ++i) {
    int idx = t + i * 256;
    int nn = idx >> 6, kk = idx & 63;
    Wt[(size_t)(n0 + nn) * DDIM + k0 + kk] = (_Float16)tile[kk][nn];
  }
}

// ---------------- K1: RMSNorm -> xn (f32) and xn (f16) ----------------
__global__ __launch_bounds__(256) void k_rmsnorm(const float* __restrict__ x,
                                                 const float* __restrict__ nw,
                                                 float* __restrict__ xnf,
                                                 _Float16* __restrict__ xnh) {
  const int l = blockIdx.x, t = threadIdx.x;
  float4 v = ((const float4*)(x + (size_t)l * DDIM))[t];
  float ss = v.x * v.x + v.y * v.y + v.z * v.z + v.w * v.w;
#pragma unroll
  for (int off = 32; off; off >>= 1) ss += __shfl_xor(ss, off, 64);
  __shared__ float sred[4];
  if ((t & 63) == 0) sred[t >> 6] = ss;
  __syncthreads();
  float tot = sred[0] + sred[1] + sred[2] + sred[3];
  float r = rsqrtf(tot * (1.0f / (float)DDIM) + 1e-6f);
  float4 wv = ((const float4*)nw)[t];
  float4 o;
  o.x = v.x * wv.x * r; o.y = v.y * wv.y * r;
  o.z = v.z * wv.z * r; o.w = v.w * wv.w * r;
  ((float4*)(xnf + (size_t)l * DDIM))[t] = o;
  half4_t h;
  h[0] = (_Float16)o.x; h[1] = (_Float16)o.y; h[2] = (_Float16)o.z; h[3] = (_Float16)o.w;
  ((half4_t*)(xnh + (size_t)l * DDIM))[t] = h;
}

// ---------------- K2: delta GEMM (f16 MFMA) + softplus + soft_clamp; writes sd = sqrt(delta) --------
// Tile M=64 (blockIdx.y), N=128 (blockIdx.x). 256 threads = 4 waves (2x2), wave tile 32x64.
// Grid (8, 64) = 512 blocks -> 2 blocks/CU.
__global__ __launch_bounds__(256) void k_gemm_delta(const _Float16* __restrict__ Ah,
                                                    const _Float16* __restrict__ Bh,
                                                    const float* __restrict__ b_delta,
                                                    float* __restrict__ sd) {
  __shared__ __align__(16) _Float16 As[64 * LDSPAD];
  __shared__ __align__(16) _Float16 Bs[128 * LDSPAD];
  const int t = threadIdx.x;
  const int w = t >> 6, lane = t & 63;
  const int quad = lane >> 4, l16 = lane & 15;
  const int wr = w >> 1, wc = w & 1;     // wave row (0..1), wave col (0..1)
  const int tileM = blockIdx.y * 64, tileN = blockIdx.x * 128;
  const int K = DDIM;

  // staging: A tile 64x32 halves = 256 x 16B segs (1/thread); B tile 128x32 = 512 segs (2/thread)
  const int sA = t, sB0 = t, sB1 = t + 256;
  const half8* gA  = (const half8*)(Ah + (size_t)(tileM + (sA  >> 2)) * K + (sA  & 3) * 8);
  const half8* gB0 = (const half8*)(Bh + (size_t)(tileN + (sB0 >> 2)) * K + (sB0 & 3) * 8);
  const half8* gB1 = (const half8*)(Bh + (size_t)(tileN + (sB1 >> 2)) * K + (sB1 & 3) * 8);
  half8* lA  = (half8*)(As + (sA  >> 2) * LDSPAD + (sA  & 3) * 8);
  half8* lB0 = (half8*)(Bs + (sB0 >> 2) * LDSPAD + (sB0 & 3) * 8);
  half8* lB1 = (half8*)(Bs + (sB1 >> 2) * LDSPAD + (sB1 & 3) * 8);

  f32x4 acc[2][4];
#pragma unroll
  for (int i = 0; i < 2; ++i)
#pragma unroll
    for (int j = 0; j < 4; ++j) acc[i][j] = (f32x4){0.f, 0.f, 0.f, 0.f};

  half8 rA = *gA, rB0 = *gB0, rB1 = *gB1;
  gA += 4; gB0 += 4; gB1 += 4;

  for (int kt = 0; kt < K / 32; ++kt) {
    __syncthreads();
    *lA = rA; *lB0 = rB0; *lB1 = rB1;
    __syncthreads();
    if (kt < K / 32 - 1) {
      rA = *gA; rB0 = *gB0; rB1 = *gB1;
      gA += 4; gB0 += 4; gB1 += 4;
    }
    half8 af[2], bf[4];
#pragma unroll
    for (int i = 0; i < 2; ++i)
      af[i] = *(const half8*)(As + (wr * 32 + i * 16 + l16) * LDSPAD + quad * 8);
#pragma unroll
    for (int j = 0; j < 4; ++j)
      bf[j] = *(const half8*)(Bs + (wc * 64 + j * 16 + l16) * LDSPAD + quad * 8);
#pragma unroll
    for (int i = 0; i < 2; ++i)
#pragma unroll
      for (int j = 0; j < 4; ++j)
        acc[i][j] = __builtin_amdgcn_mfma_f32_16x16x32_f16(af[i], bf[j], acc[i][j], 0, 0, 0);
  }

  // epilogue: delta = soft_clamp(softplus(z + b)); store sqrt(delta)
  const float cC = 5.00005f, cH = 4.99995f, invH = 1.0f / 4.99995f;
  float bdl[4];
#pragma unroll
  for (int j = 0; j < 4; ++j) bdl[j] = b_delta[tileN + wc * 64 + j * 16 + l16];
#pragma unroll
  for (int i = 0; i < 2; ++i) {
#pragma unroll
    for (int r = 0; r < 4; ++r) {
      int row = tileM + wr * 32 + i * 16 + quad * 4 + r;
#pragma unroll
      for (int j = 0; j < 4; ++j) {
        int col = tileN + wc * 64 + j * 16 + l16;
        float z = acc[i][j][r] + bdl[j];
        float sp = fmaxf(z, 0.f) + log1pf(__expf(-fabsf(z)));   // stable softplus
        float dt = cC + cH * tanhf((sp - cC) * invH);           // soft clamp to [1e-4, 10]
        sd[(size_t)row * DDIM + col] = sqrtf(dt);
      }
    }
  }
}

// ---------------- K3: Bp = xn@W_B, C = xn@W_C -> bpc[l][n] = {Bp, C} ----------------
__global__ __launch_bounds__(256) void k_bpc(const float* __restrict__ xnf,
                                             const float* __restrict__ WB,
                                             const float* __restrict__ WC,
                                             float* __restrict__ bpcf) {
  const int l = blockIdx.x, t = threadIdx.x;
  const int no = t & 31, p = t >> 5;          // 32 outputs x 8 k-partitions
  const float* W = (no < 16) ? WB : WC;
  const int n = no & 15;
  const float* xr = xnf + (size_t)l * DDIM + p * 128;
  float s = 0.f;
#pragma unroll 4
  for (int k = 0; k < 128; ++k) s = fmaf(xr[k], W[(p * 128 + k) * NSTATE + n], s);
  __shared__ float sh[256];
  sh[t] = s;
  __syncthreads();
  if (t < 32) {
    float tot = 0.f;
#pragma unroll
    for (int q = 0; q < 8; ++q) tot += sh[no + 32 * q];
    bpcf[(size_t)l * 32 + n * 2 + (no >> 4)] = tot;   // float2 {Bp, C} per (l,n)
  }
}

// ---------------- scan math ----------------
// hd = delta*0.5*A (<=0), ab = (1+hd)/(1-hd), bx = sqrt(delta)*Bp*xn/(1-hd)

// K4a: per-chunk local scan -> {prod A_bar, h_end}
__global__ __launch_bounds__(256) void k_scan1(const float* __restrict__ sd,
                                               const float* __restrict__ xnf,
                                               const float2* __restrict__ bpc,
                                               const float* __restrict__ A_log,
                                               float2* __restrict__ Ph) {
  const int d = blockIdx.x * 256 + threadIdx.x;
  const int c = blockIdx.y;
  float halfA[NSTATE], h[NSTATE], P[NSTATE];
#pragma unroll
  for (int n = 0; n < NSTATE; ++n) {
    halfA[n] = -0.5f * __expf(A_log[d * NSTATE + n]);
    h[n] = 0.f; P[n] = 1.f;
  }
  const float* sdr = sd + (size_t)c * CLEN * DDIM + d;
  const float* xr = xnf + (size_t)c * CLEN * DDIM + d;
  const float2* br = bpc + (size_t)c * CLEN * NSTATE;
#pragma unroll 2
  for (int i = 0; i < CLEN; ++i) {
    float sdv = sdr[(size_t)i * DDIM];
    float xv = xr[(size_t)i * DDIM];
    float dsq = sdv * sdv;        // delta
    float sdx = sdv * xv;         // sqrt(delta)*xn
#pragma unroll
    for (int n = 0; n < NSTATE; ++n) {
      float2 bc = br[i * NSTATE + n];     // block-uniform -> scalar loads
      float hd = dsq * halfA[n];
      float di = __builtin_amdgcn_rcpf(1.0f - hd);  // 1-hd >= 1 always
      float ab = fmaf(hd, di, di);
      h[n] = fmaf(ab, h[n], sdx * bc.x * di);
      P[n] *= ab;
    }
  }
#pragma unroll
  for (int n = 0; n < NSTATE; ++n)
    Ph[((size_t)c * NSTATE + n) * DDIM + d] = make_float2(P[n], h[n]);
}

// K4c: sequential combine across chunks -> chunk-entry states (batched prefetch)
__global__ __launch_bounds__(64) void k_comb(const float2* __restrict__ Ph,
                                             float* __restrict__ Hinit) {
  const int g = blockIdx.x * 64 + threadIdx.x;   // g = n*1024 + d, 16384 total
  float H = 0.f;
  for (int cb = 0; cb < NCHUNK; cb += 8) {
    float2 ph[8];
#pragma unroll
    for (int u = 0; u < 8; ++u)
      ph[u] = Ph[(size_t)(cb + u) * (DDIM * NSTATE) + g];
#pragma unroll
    for (int u = 0; u < 8; ++u) {
      Hinit[(size_t)(cb + u) * (DDIM * NSTATE) + g] = H;
      H = fmaf(ph[u].x, H, ph[u].y);
    }
  }
}

// K4b: re-run chunk scans with correct h0, emit y
__global__ __launch_bounds__(256) void k_scan2(const float* __restrict__ sd,
                                               const float* __restrict__ xnf,
                                               const float2* __restrict__ bpc,
                                               const float* __restrict__ A_log,
                                               const float* __restrict__ Hinit,
                                               const float* __restrict__ Dskip,
                                               float* __restrict__ y) {
  const int d = blockIdx.x * 256 + threadIdx.x;
  const int c = blockIdx.y;
  float halfA[NSTATE], h[NSTATE];
#pragma unroll
  for (int n = 0; n < NSTATE; ++n) {
    halfA[n] = -0.5f * __expf(A_log[d * NSTATE + n]);
    h[n] = Hinit[(size_t)c * (DDIM * NSTATE) + n * DDIM + d];
  }
  const float dsk = Dskip[d];
  const float* sdr = sd + (size_t)c * CLEN * DDIM + d;
  const float* xr = xnf + (size_t)c * CLEN * DDIM + d;
  const float2* br = bpc + (size_t)c * CLEN * NSTATE;
  float* yr = y + (size_t)c * CLEN * DDIM + d;
#pragma unroll 2
  for (int i = 0; i < CLEN; ++i) {
    float sdv = sdr[(size_t)i * DDIM];
    float xv = xr[(size_t)i * DDIM];
    float dsq = sdv * sdv;
    float sdx = sdv * xv;
    float acc = dsk * xv;
#pragma unroll
    for (int n = 0; n < NSTATE; ++n) {
      float2 bc = br[i * NSTATE + n];
      float hd = dsq * halfA[n];
      float di = __builtin_amdgcn_rcpf(1.0f - hd);
      float ab = fmaf(hd, di, di);
      h[n] = fmaf(ab, h[n], sdx * bc.x * di);
      acc = fmaf(bc.y, h[n], acc);
    }
    yr[(size_t)i * DDIM] = acc;
  }
}

// ---------------- launch ----------------
extern "C" void kernel_launch(void* const* d_in, const int* in_sizes, int n_in,
                              void* d_out, int out_size, void* d_ws, size_t ws_size,
                              hipStream_t stream) {
  const float* x       = (const float*)d_in[0];
  const float* A_log   = (const float*)d_in[1];
  const float* W_delta = (const float*)d_in[2];
  const float* b_delta = (const float*)d_in[3];
  const float* W_B     = (const float*)d_in[4];
  const float* W_C     = (const float*)d_in[5];
  const float* D_skip  = (const float*)d_in[6];
  const float* norm_w  = (const float*)d_in[7];
  float* y = (float*)d_out;

  char* ws = (char*)d_ws;
  const size_t MB = 1024 * 1024;
  float*    xnf = (float*)(ws);                 // 16 MB  xn f32
  _Float16* xnh = (_Float16*)(ws + 16 * MB);    //  8 MB  xn f16
  _Float16* Wth = (_Float16*)(ws + 24 * MB);    //  2 MB  W_delta^T f16
  float*    sd  = (float*)(ws + 26 * MB);       // 16 MB  sqrt(delta)
  float2*   bpc = (float2*)(ws + 42 * MB);      // .5 MB  {Bp, C}
  float2*   Ph  = (float2*)(ws + 43 * MB);      // 16 MB  {prodA, h_end}
  float*    Hin = (float*)(ws + 59 * MB);       //  8 MB  chunk-entry states
  (void)ws_size; (void)in_sizes; (void)n_in; (void)out_size;

  hipLaunchKernelGGL(k_transpose, dim3(16, 16), dim3(256), 0, stream, W_delta, Wth);
  hipLaunchKernelGGL(k_rmsnorm, dim3(LDIM), dim3(256), 0, stream, x, norm_w, xnf, xnh);
  hipLaunchKernelGGL(k_gemm_delta, dim3(DDIM / 128, LDIM / 64), dim3(256), 0, stream,
                     xnh, Wth, b_delta, sd);
  hipLaunchKernelGGL(k_bpc, dim3(LDIM), dim3(256), 0, stream, xnf, W_B, W_C, (float*)bpc);
  hipLaunchKernelGGL(k_scan1, dim3(DDIM / 256, NCHUNK), dim3(256), 0, stream,
                     sd, xnf, bpc, A_log, Ph);
  hipLaunchKernelGGL(k_comb, dim3(256), dim3(64), 0, stream, Ph, Hin);
  hipLaunchKernelGGL(k_scan2, dim3(DDIM / 256, NCHUNK), dim3(256), 0, stream,
                     sd, xnf, bpc, A_log, Hin, D_skip, y);
}

// Round 3
// 175.518 us; speedup vs baseline: 1.3144x; 1.2029x over previous
//
#include <hip/hip_runtime.h>
#include <hip/hip_fp16.h>
#include <cmath>

typedef _Float16 half8 __attribute__((ext_vector_type(8)));
typedef _Float16 half4_t __attribute__((ext_vector_type(4)));
typedef float f32x4 __attribute__((ext_vector_type(4)));

#define LDIM 4096
#define DDIM 1024
#define NSTATE 16
#define NCHUNK 128
#define CLEN 32

#define GLD16(g, l) __builtin_amdgcn_global_load_lds( \
    (const __attribute__((address_space(1))) void*)(g), \
    (__attribute__((address_space(3))) void*)(l), 16, 0, 0)

// ---- K0: prep. bx<16: transpose W_delta (k,n)->Wt(n,k) f16. bx==16: pack W_B/W_C -> BCe(32,1024) f16
__global__ __launch_bounds__(256) void k_prep(const float* __restrict__ W,
                                              const float* __restrict__ WB,
                                              const float* __restrict__ WC,
                                              _Float16* __restrict__ Wt,
                                              _Float16* __restrict__ BCe) {
  const int t = threadIdx.x;
  if (blockIdx.x < 16) {
    __shared__ float tile[64][65];
    const int n0 = blockIdx.x * 64, k0 = blockIdx.y * 64;
#pragma unroll
    for (int i = 0; i < 16; ++i) {
      int idx = t + i * 256;
      int kk = idx >> 6, nn = idx & 63;
      tile[kk][nn] = W[(size_t)(k0 + kk) * DDIM + n0 + nn];
    }
    __syncthreads();
#pragma unroll
    for (int i = 0; i < 16; ++i) {
      int idx = t + i * 256;
      int nn = idx >> 6, kk = idx & 63;
      Wt[(size_t)(n0 + nn) * DDIM + k0 + kk] = (_Float16)tile[kk][nn];
    }
  } else {
    // rows 2*by, 2*by+1 of BCe; BCe[r][k] = (r odd ? WC : WB)[k][r>>1]
#pragma unroll
    for (int rr = 0; rr < 2; ++rr) {
      int r = 2 * blockIdx.y + rr;
      const float* src = (r & 1) ? WC : WB;
      int n = r >> 1;
#pragma unroll
      for (int j = 0; j < 4; ++j) {
        int k = t * 4 + j;
        BCe[(size_t)r * DDIM + k] = (_Float16)src[(size_t)k * NSTATE + n];
      }
    }
  }
}

// ---- K1: RMSNorm -> xn f16 only
__global__ __launch_bounds__(256) void k_rmsnorm(const float* __restrict__ x,
                                                 const float* __restrict__ nw,
                                                 _Float16* __restrict__ xnh) {
  const int l = blockIdx.x, t = threadIdx.x;
  float4 v = ((const float4*)(x + (size_t)l * DDIM))[t];
  float ss = v.x * v.x + v.y * v.y + v.z * v.z + v.w * v.w;
#pragma unroll
  for (int off = 32; off; off >>= 1) ss += __shfl_xor(ss, off, 64);
  __shared__ float sred[4];
  if ((t & 63) == 0) sred[t >> 6] = ss;
  __syncthreads();
  float tot = sred[0] + sred[1] + sred[2] + sred[3];
  float r = rsqrtf(tot * (1.0f / (float)DDIM) + 1e-6f);
  float4 wv = ((const float4*)nw)[t];
  half4_t h;
  h[0] = (_Float16)(v.x * wv.x * r); h[1] = (_Float16)(v.y * wv.y * r);
  h[2] = (_Float16)(v.z * wv.z * r); h[3] = (_Float16)(v.w * wv.w * r);
  ((half4_t*)(xnh + (size_t)l * DDIM))[t] = h;
}

// ---- K2: fused GEMM. C = xnh @ Wt^T (delta path, N=1024) + BC K-sliced partials.
// grid (8, 32): tileN = bx*128, tileM = by*128. 256 thr = 4 waves (2x2), wave tile 64x64.
// dbuf LDS + global_load_lds, one barrier per kt.
__global__ __launch_bounds__(256) void k_gemm(const _Float16* __restrict__ Ah,
                                              const _Float16* __restrict__ Bh,
                                              const _Float16* __restrict__ B2h,
                                              const float* __restrict__ b_delta,
                                              _Float16* __restrict__ sdh,
                                              float* __restrict__ bpp) {
  __shared__ __align__(16) _Float16 As[2][128 * 32];
  __shared__ __align__(16) _Float16 Bs[2][128 * 32];
  __shared__ __align__(16) _Float16 B2s[2][32 * 32];
  const int t = threadIdx.x;
  const int w = t >> 6, lane = t & 63;
  const int quad = lane >> 4, l16 = lane & 15;
  const int wr = w >> 1, wc = w & 1;
  const int bx = blockIdx.x, by = blockIdx.y;
  const int tileM = by * 128, tileN = bx * 128;

  // staging: lane covers 16B seg: row = base + (lane>>2), kseg = lane&3
  const int srow = lane >> 2, scol = (lane & 3) * 8;
  const _Float16* gA0 = Ah + (size_t)(tileM + w * 32 + srow) * DDIM + scol;
  const _Float16* gB0 = Bh + (size_t)(tileN + w * 32 + srow) * DDIM + scol;
  const _Float16* gC0 = B2h + (size_t)(w * 16 + srow) * DDIM + scol;  // w<2 only

  f32x4 acc[4][4], acc2[4];
#pragma unroll
  for (int i = 0; i < 4; ++i) {
    acc2[i] = (f32x4){0.f, 0.f, 0.f, 0.f};
#pragma unroll
    for (int j = 0; j < 4; ++j) acc[i][j] = (f32x4){0.f, 0.f, 0.f, 0.f};
  }

  auto stage = [&](int kt, int p) {
    const int ko = kt * 32;
    GLD16(gA0 + ko,              &As[p][(w * 32) * 32]);
    GLD16(gA0 + 16 * DDIM + ko,  &As[p][(w * 32 + 16) * 32]);
    GLD16(gB0 + ko,              &Bs[p][(w * 32) * 32]);
    GLD16(gB0 + 16 * DDIM + ko,  &Bs[p][(w * 32 + 16) * 32]);
    if ((kt >> 2) == bx && w < 2)
      GLD16(gC0 + ko,            &B2s[p][(w * 16) * 32]);
  };

  stage(0, 0);
  for (int kt = 0; kt < 32; ++kt) {
    const int p = kt & 1;
    __syncthreads();                 // drains vmcnt -> buf p ready; guards p^1 overwrite
    if (kt < 31) stage(kt + 1, p ^ 1);
    half8 af[4], bf[4];
#pragma unroll
    for (int i = 0; i < 4; ++i)
      af[i] = *(const half8*)&As[p][(wr * 64 + i * 16 + l16) * 32 + quad * 8];
#pragma unroll
    for (int j = 0; j < 4; ++j)
      bf[j] = *(const half8*)&Bs[p][(wc * 64 + j * 16 + l16) * 32 + quad * 8];
#pragma unroll
    for (int i = 0; i < 4; ++i)
#pragma unroll
      for (int j = 0; j < 4; ++j)
        acc[i][j] = __builtin_amdgcn_mfma_f32_16x16x32_f16(af[i], bf[j], acc[i][j], 0, 0, 0);
    if ((kt >> 2) == bx) {
      half8 cf = *(const half8*)&B2s[p][(wc * 16 + l16) * 32 + quad * 8];
#pragma unroll
      for (int i = 0; i < 4; ++i)
        acc2[i] = __builtin_amdgcn_mfma_f32_16x16x32_f16(af[i], cf, acc2[i], 0, 0, 0);
    }
  }

  // epilogue: delta = soft_clamp(softplus(z+b)) -> sdh = sqrt(delta) f16
  const float cC = 5.00005f, cH = 4.99995f, invH = 1.0f / 4.99995f;
  float bdl[4];
#pragma unroll
  for (int j = 0; j < 4; ++j) bdl[j] = b_delta[tileN + wc * 64 + j * 16 + l16];
#pragma unroll
  for (int i = 0; i < 4; ++i) {
#pragma unroll
    for (int r = 0; r < 4; ++r) {
      int row = tileM + wr * 64 + i * 16 + quad * 4 + r;
#pragma unroll
      for (int j = 0; j < 4; ++j) {
        int col = tileN + wc * 64 + j * 16 + l16;
        float z = acc[i][j][r] + bdl[j];
        float e = __expf(-fabsf(z));
        float sp = fmaxf(z, 0.f) + __logf(1.0f + e);
        float tt = (sp - cC) * invH;
        float e2 = __expf(-2.0f * fabsf(tt));
        float th = copysignf((1.0f - e2) / (1.0f + e2), tt);
        float dt = fmaf(cH, th, cC);
        sdh[(size_t)row * DDIM + col] = (_Float16)sqrtf(dt);
      }
    }
  }
  // BC partial plane bx, rows [tileM, tileM+128), cols wc*16+l16
#pragma unroll
  for (int i = 0; i < 4; ++i) {
#pragma unroll
    for (int r = 0; r < 4; ++r) {
      int row = tileM + wr * 64 + i * 16 + quad * 4 + r;
      bpp[((size_t)bx * LDIM + row) * 32 + wc * 16 + l16] = acc2[i][r];
    }
  }
}

// ---- bc prologue helper: sum 8 K-slice planes for chunk c into LDS (32 rows x 16 float2)
__device__ inline void load_bc(const float* __restrict__ bpp, int c, int t, float2* bcs) {
#pragma unroll
  for (int u = t; u < CLEN * NSTATE; u += 256) {
    int l = u >> 4, n2 = (u & 15) * 2;
    float bs = 0.f, cs = 0.f;
#pragma unroll
    for (int p = 0; p < 8; ++p) {
      size_t base = ((size_t)p * LDIM + c * CLEN + l) * 32;
      bs += bpp[base + n2];
      cs += bpp[base + n2 + 1];
    }
    bcs[u] = make_float2(bs, cs);
  }
}

// ---- K3: per-chunk local scan -> {prodA, h_end} f32
__global__ __launch_bounds__(256) void k_scan1(const _Float16* __restrict__ sdh,
                                               const _Float16* __restrict__ xnh,
                                               const float* __restrict__ bpp,
                                               const float* __restrict__ A_log,
                                               float2* __restrict__ Ph) {
  __shared__ float2 bcs[CLEN * NSTATE];
  const int t = threadIdx.x;
  const int d = blockIdx.x * 256 + t;
  const int c = blockIdx.y;
  load_bc(bpp, c, t, bcs);
  float halfA[NSTATE], h[NSTATE], P[NSTATE];
#pragma unroll
  for (int n = 0; n < NSTATE; ++n) {
    halfA[n] = -0.5f * __expf(A_log[d * NSTATE + n]);
    h[n] = 0.f; P[n] = 1.f;
  }
  __syncthreads();
  const _Float16* sdr = sdh + (size_t)c * CLEN * DDIM + d;
  const _Float16* xr = xnh + (size_t)c * CLEN * DDIM + d;
#pragma unroll 2
  for (int i = 0; i < CLEN; ++i) {
    float sdv = (float)sdr[(size_t)i * DDIM];
    float xv = (float)xr[(size_t)i * DDIM];
    float dsq = sdv * sdv;
    float sdx = sdv * xv;
#pragma unroll
    for (int n = 0; n < NSTATE; ++n) {
      float2 bc = bcs[i * NSTATE + n];
      float hd = dsq * halfA[n];
      float di = __builtin_amdgcn_rcpf(1.0f - hd);
      float ab = fmaf(hd, di, di);
      h[n] = fmaf(ab, h[n], sdx * bc.x * di);
      P[n] *= ab;
    }
  }
#pragma unroll
  for (int n = 0; n < NSTATE; ++n)
    Ph[((size_t)c * NSTATE + n) * DDIM + d] = make_float2(P[n], h[n]);
}

// ---- K4: sequential combine across chunks (batched prefetch)
__global__ __launch_bounds__(64) void k_comb(const float2* __restrict__ Ph,
                                             float* __restrict__ Hinit) {
  const int g = blockIdx.x * 64 + threadIdx.x;
  float H = 0.f;
  for (int cb = 0; cb < NCHUNK; cb += 8) {
    float2 ph[8];
#pragma unroll
    for (int u = 0; u < 8; ++u)
      ph[u] = Ph[(size_t)(cb + u) * (DDIM * NSTATE) + g];
#pragma unroll
    for (int u = 0; u < 8; ++u) {
      Hinit[(size_t)(cb + u) * (DDIM * NSTATE) + g] = H;
      H = fmaf(ph[u].x, H, ph[u].y);
    }
  }
}

// ---- K5: re-run chunk scans with true h0, emit y
__global__ __launch_bounds__(256) void k_scan2(const _Float16* __restrict__ sdh,
                                               const _Float16* __restrict__ xnh,
                                               const float* __restrict__ bpp,
                                               const float* __restrict__ A_log,
                                               const float* __restrict__ Hinit,
                                               const float* __restrict__ Dskip,
                                               float* __restrict__ y) {
  __shared__ float2 bcs[CLEN * NSTATE];
  const int t = threadIdx.x;
  const int d = blockIdx.x * 256 + t;
  const int c = blockIdx.y;
  load_bc(bpp, c, t, bcs);
  float halfA[NSTATE], h[NSTATE];
#pragma unroll
  for (int n = 0; n < NSTATE; ++n) {
    halfA[n] = -0.5f * __expf(A_log[d * NSTATE + n]);
    h[n] = Hinit[(size_t)c * (DDIM * NSTATE) + n * DDIM + d];
  }
  const float dsk = Dskip[d];
  __syncthreads();
  const _Float16* sdr = sdh + (size_t)c * CLEN * DDIM + d;
  const _Float16* xr = xnh + (size_t)c * CLEN * DDIM + d;
  float* yr = y + (size_t)c * CLEN * DDIM + d;
#pragma unroll 2
  for (int i = 0; i < CLEN; ++i) {
    float sdv = (float)sdr[(size_t)i * DDIM];
    float xv = (float)xr[(size_t)i * DDIM];
    float dsq = sdv * sdv;
    float sdx = sdv * xv;
    float acc = dsk * xv;
#pragma unroll
    for (int n = 0; n < NSTATE; ++n) {
      float2 bc = bcs[i * NSTATE + n];
      float hd = dsq * halfA[n];
      float di = __builtin_amdgcn_rcpf(1.0f - hd);
      float ab = fmaf(hd, di, di);
      h[n] = fmaf(ab, h[n], sdx * bc.x * di);
      acc = fmaf(bc.y, h[n], acc);
    }
    yr[(size_t)i * DDIM] = acc;
  }
}

// ---------------- launch ----------------
extern "C" void kernel_launch(void* const* d_in, const int* in_sizes, int n_in,
                              void* d_out, int out_size, void* d_ws, size_t ws_size,
                              hipStream_t stream) {
  const float* x       = (const float*)d_in[0];
  const float* A_log   = (const float*)d_in[1];
  const float* W_delta = (const float*)d_in[2];
  const float* b_delta = (const float*)d_in[3];
  const float* W_B     = (const float*)d_in[4];
  const float* W_C     = (const float*)d_in[5];
  const float* D_skip  = (const float*)d_in[6];
  const float* norm_w  = (const float*)d_in[7];
  float* y = (float*)d_out;

  char* ws = (char*)d_ws;
  const size_t MB = 1024 * 1024;
  _Float16* xnh = (_Float16*)(ws);              //  8 MB xn f16
  _Float16* Wt  = (_Float16*)(ws + 8 * MB);     //  2 MB W_delta^T f16
  _Float16* BCe = (_Float16*)(ws + 10 * MB);    // 64 KB packed W_B/W_C f16 (32 x 1024)
  _Float16* sdh = (_Float16*)(ws + 11 * MB);    //  8 MB sqrt(delta) f16
  float*    bpp = (float*)(ws + 19 * MB);       //  4 MB BC partials [8][4096][32]
  float2*   Ph  = (float2*)(ws + 23 * MB);      // 16 MB {prodA, h_end}
  float*    Hin = (float*)(ws + 39 * MB);       //  8 MB chunk-entry states
  (void)ws_size; (void)in_sizes; (void)n_in; (void)out_size;

  hipLaunchKernelGGL(k_prep, dim3(17, 16), dim3(256), 0, stream, W_delta, W_B, W_C, Wt, BCe);
  hipLaunchKernelGGL(k_rmsnorm, dim3(LDIM), dim3(256), 0, stream, x, norm_w, xnh);
  hipLaunchKernelGGL(k_gemm, dim3(8, 32), dim3(256), 0, stream, xnh, Wt, BCe, b_delta, sdh, bpp);
  hipLaunchKernelGGL(k_scan1, dim3(4, NCHUNK), dim3(256), 0, stream, sdh, xnh, bpp, A_log, Ph);
  hipLaunchKernelGGL(k_comb, dim3(256), dim3(64), 0, stream, Ph, Hin);
  hipLaunchKernelGGL(k_scan2, dim3(4, NCHUNK), dim3(256), 0, stream,
                     sdh, xnh, bpp, A_log, Hin, D_skip, y);
}

// Round 7
// 167.082 us; speedup vs baseline: 1.3807x; 1.0505x over previous
//
#include <hip/hip_runtime.h>
#include <hip/hip_fp16.h>
#include <cmath>

typedef _Float16 half8 __attribute__((ext_vector_type(8)));
typedef _Float16 half4_t __attribute__((ext_vector_type(4)));
typedef float f32x4 __attribute__((ext_vector_type(4)));

#define LDIM 4096
#define DDIM 1024
#define NSTATE 16
#define NCHUNK 128
#define CLEN 32

#define GLD16(g, l) __builtin_amdgcn_global_load_lds( \
    (const __attribute__((address_space(1))) void*)(g), \
    (__attribute__((address_space(3))) void*)(l), 16, 0, 0)

// ---------------- K1: prep (W transpose + BC pack) + RMSNorm + zero bpc ----------------
__global__ __launch_bounds__(256) void k_prep_norm(const float* __restrict__ x,
                                                   const float* __restrict__ nw,
                                                   const float* __restrict__ W,
                                                   const float* __restrict__ WB,
                                                   const float* __restrict__ WC,
                                                   _Float16* __restrict__ xnh,
                                                   _Float16* __restrict__ Wt,
                                                   _Float16* __restrict__ BCe,
                                                   float* __restrict__ bpc) {
  const int b = blockIdx.x, t = threadIdx.x;
  if (b < 4096) {
    const int l = b;
    if (t < 32) bpc[(size_t)l * 32 + t] = 0.f;      // zero BC accumulator
    float4 v = ((const float4*)(x + (size_t)l * DDIM))[t];
    float ss = v.x * v.x + v.y * v.y + v.z * v.z + v.w * v.w;
#pragma unroll
    for (int off = 32; off; off >>= 1) ss += __shfl_xor(ss, off, 64);
    __shared__ float sred[4];
    if ((t & 63) == 0) sred[t >> 6] = ss;
    __syncthreads();
    float tot = sred[0] + sred[1] + sred[2] + sred[3];
    float r = rsqrtf(tot * (1.0f / (float)DDIM) + 1e-6f);
    float4 wv = ((const float4*)nw)[t];
    half4_t h;
    h[0] = (_Float16)(v.x * wv.x * r); h[1] = (_Float16)(v.y * wv.y * r);
    h[2] = (_Float16)(v.z * wv.z * r); h[3] = (_Float16)(v.w * wv.w * r);
    ((half4_t*)(xnh + (size_t)l * DDIM))[t] = h;
  } else if (b < 4352) {
    __shared__ float tile[64][65];
    const int bb = b - 4096;
    const int n0 = (bb & 15) * 64, k0 = (bb >> 4) * 64;
#pragma unroll
    for (int i = 0; i < 16; ++i) {
      int idx = t + i * 256;
      int kk = idx >> 6, nn = idx & 63;
      tile[kk][nn] = W[(size_t)(k0 + kk) * DDIM + n0 + nn];
    }
    __syncthreads();
#pragma unroll
    for (int i = 0; i < 16; ++i) {
      int idx = t + i * 256;
      int nn = idx >> 6, kk = idx & 63;
      Wt[(size_t)(n0 + nn) * DDIM + k0 + kk] = (_Float16)tile[kk][nn];
    }
  } else {
    const int by2 = b - 4352;
#pragma unroll
    for (int rr = 0; rr < 2; ++rr) {
      int r = 2 * by2 + rr;
      const float* src = (r & 1) ? WC : WB;
      int n = r >> 1;
#pragma unroll
      for (int j = 0; j < 4; ++j) {
        int k = t * 4 + j;
        BCe[(size_t)r * DDIM + k] = (_Float16)src[(size_t)k * NSTATE + n];
      }
    }
  }
}

// ---------------- K2: GEMM (round-4/6 phase-G geometry, standalone) ----------------
// Tile M=128, N=64. grid 512 1-D: bx = bid&15 (N), by = bid>>4 (M). 4 waves 2x2,
// wave tile 64x32. GLD16 double-buffered staging. BC K-sliced: kt>>1 == bx,
// accumulated via atomicAdd into bpc (zeroed by k_prep_norm).
__global__ __launch_bounds__(256, 2) void k_gemm64(const _Float16* __restrict__ Ah,
                                                   const _Float16* __restrict__ Bh,
                                                   const _Float16* __restrict__ B2h,
                                                   const float* __restrict__ b_delta,
                                                   _Float16* __restrict__ sdh,
                                                   float* __restrict__ bpc) {
  __shared__ __align__(16) _Float16 As[2][128 * 32];
  __shared__ __align__(16) _Float16 Bs[2][64 * 32];
  __shared__ __align__(16) _Float16 B2s[2][32 * 32];
  const int t = threadIdx.x;
  const int w = t >> 6, lane = t & 63;
  const int quad = lane >> 4, l16 = lane & 15;
  const int wr = w >> 1, wc = w & 1;
  const int bid = blockIdx.x;
  const int bx = bid & 15, by = bid >> 4;
  const int tileM = by * 128, tileN = bx * 64;
  const int srow = lane >> 2, scol = (lane & 3) * 8;
  const _Float16* gA0 = Ah + (size_t)(tileM + w * 32 + srow) * DDIM + scol;
  const _Float16* gB0 = Bh + (size_t)(tileN + w * 16 + srow) * DDIM + scol;
  const _Float16* gC0 = B2h + (size_t)(w * 16 + srow) * DDIM + scol;  // w<2 only

  f32x4 acc[4][2], acc2[4];
#pragma unroll
  for (int i = 0; i < 4; ++i) {
    acc2[i] = (f32x4){0.f, 0.f, 0.f, 0.f};
#pragma unroll
    for (int j = 0; j < 2; ++j) acc[i][j] = (f32x4){0.f, 0.f, 0.f, 0.f};
  }

  auto stage = [&](int kt, int p) {
    const int ko = kt * 32;
    GLD16(gA0 + ko,             &As[p][(w * 32) * 32]);
    GLD16(gA0 + 16 * DDIM + ko, &As[p][(w * 32 + 16) * 32]);
    GLD16(gB0 + ko,             &Bs[p][(w * 16) * 32]);
    if ((kt >> 1) == bx && w < 2)
      GLD16(gC0 + ko,           &B2s[p][(w * 16) * 32]);
  };

  stage(0, 0);
  for (int kt = 0; kt < 32; ++kt) {
    const int p = kt & 1;
    __syncthreads();               // drains vmcnt: buf p ready; guards p^1 overwrite
    if (kt < 31) stage(kt + 1, p ^ 1);
    half8 af[4], bf[2];
#pragma unroll
    for (int i = 0; i < 4; ++i)
      af[i] = *(const half8*)&As[p][(wr * 64 + i * 16 + l16) * 32 + quad * 8];
#pragma unroll
    for (int j = 0; j < 2; ++j)
      bf[j] = *(const half8*)&Bs[p][(wc * 32 + j * 16 + l16) * 32 + quad * 8];
#pragma unroll
    for (int i = 0; i < 4; ++i)
#pragma unroll
      for (int j = 0; j < 2; ++j)
        acc[i][j] = __builtin_amdgcn_mfma_f32_16x16x32_f16(af[i], bf[j], acc[i][j], 0, 0, 0);
    if ((kt >> 1) == bx) {
      half8 cf = *(const half8*)&B2s[p][(wc * 16 + l16) * 32 + quad * 8];
#pragma unroll
      for (int i = 0; i < 4; ++i)
        acc2[i] = __builtin_amdgcn_mfma_f32_16x16x32_f16(af[i], cf, acc2[i], 0, 0, 0);
    }
  }

  // epilogue: delta = soft_clamp(softplus(z+b)) -> sdh = sqrt(delta) f16
  const float cC = 5.00005f, cH = 4.99995f, invH = 1.0f / 4.99995f;
  float bdl[2];
#pragma unroll
  for (int j = 0; j < 2; ++j) bdl[j] = b_delta[tileN + wc * 32 + j * 16 + l16];
#pragma unroll
  for (int i = 0; i < 4; ++i) {
#pragma unroll
    for (int r = 0; r < 4; ++r) {
      int row = tileM + wr * 64 + i * 16 + quad * 4 + r;
#pragma unroll
      for (int j = 0; j < 2; ++j) {
        int col = tileN + wc * 32 + j * 16 + l16;
        float z = acc[i][j][r] + bdl[j];
        float e = __expf(-fabsf(z));
        float sp = fmaxf(z, 0.f) + __logf(1.0f + e);
        float tt = (sp - cC) * invH;
        float e2 = __expf(-2.0f * fabsf(tt));
        float th = copysignf((1.0f - e2) / (1.0f + e2), tt);
        float dt = fmaf(cH, th, cC);
        sdh[(size_t)row * DDIM + col] = (_Float16)sqrtf(dt);
      }
      atomicAdd(&bpc[(size_t)row * 32 + wc * 16 + l16], acc2[i][r]);
    }
  }
}

// ---------------- K3: per-chunk local scan -> {prodA, h_end} ----------------
__global__ __launch_bounds__(256) void k_scan1(const _Float16* __restrict__ sdh,
                                               const _Float16* __restrict__ xnh,
                                               const float* __restrict__ bpc,
                                               const float* __restrict__ A_log,
                                               float2* __restrict__ Ph) {
  __shared__ float2 bcs[CLEN * NSTATE];
  const int t = threadIdx.x;
  const int d = blockIdx.x * 256 + t;
  const int c = blockIdx.y;
#pragma unroll
  for (int u = t; u < CLEN * NSTATE; u += 256) {
    int l = u >> 4, n2 = (u & 15) * 2;
    bcs[u] = *(const float2*)&bpc[(size_t)(c * CLEN + l) * 32 + n2];
  }
  float halfA[NSTATE], h[NSTATE], P[NSTATE];
#pragma unroll
  for (int n = 0; n < NSTATE; ++n) {
    halfA[n] = -0.5f * __expf(A_log[d * NSTATE + n]);
    h[n] = 0.f; P[n] = 1.f;
  }
  __syncthreads();
  const _Float16* sdr = sdh + (size_t)c * CLEN * DDIM + d;
  const _Float16* xr = xnh + (size_t)c * CLEN * DDIM + d;
#pragma unroll 2
  for (int i = 0; i < CLEN; ++i) {
    float sdv = (float)sdr[(size_t)i * DDIM];
    float xv = (float)xr[(size_t)i * DDIM];
    float dsq = sdv * sdv;
    float sdx = sdv * xv;
#pragma unroll
    for (int n = 0; n < NSTATE; ++n) {
      float2 bc = bcs[i * NSTATE + n];
      float hd = dsq * halfA[n];
      float di = __builtin_amdgcn_rcpf(1.0f - hd);
      float ab = fmaf(hd, di, di);
      h[n] = fmaf(ab, h[n], sdx * bc.x * di);
      P[n] *= ab;
    }
  }
#pragma unroll
  for (int n = 0; n < NSTATE; ++n)
    Ph[((size_t)c * NSTATE + n) * DDIM + d] = make_float2(P[n], h[n]);
}

// ---------------- K4: sequential combine across chunks ----------------
__global__ __launch_bounds__(64) void k_comb(const float2* __restrict__ Ph,
                                             float* __restrict__ Hinit) {
  const int g = blockIdx.x * 64 + threadIdx.x;
  float H = 0.f;
  for (int cb = 0; cb < NCHUNK; cb += 8) {
    float2 ph[8];
#pragma unroll
    for (int u = 0; u < 8; ++u)
      ph[u] = Ph[(size_t)(cb + u) * (DDIM * NSTATE) + g];
#pragma unroll
    for (int u = 0; u < 8; ++u) {
      Hinit[(size_t)(cb + u) * (DDIM * NSTATE) + g] = H;
      H = fmaf(ph[u].x, H, ph[u].y);
    }
  }
}

// ---------------- K5: re-run chunk scans with true h0, emit y ----------------
__global__ __launch_bounds__(256) void k_scan2(const _Float16* __restrict__ sdh,
                                               const _Float16* __restrict__ xnh,
                                               const float* __restrict__ bpc,
                                               const float* __restrict__ A_log,
                                               const float* __restrict__ Hinit,
                                               const float* __restrict__ Dskip,
                                               float* __restrict__ y) {
  __shared__ float2 bcs[CLEN * NSTATE];
  const int t = threadIdx.x;
  const int d = blockIdx.x * 256 + t;
  const int c = blockIdx.y;
#pragma unroll
  for (int u = t; u < CLEN * NSTATE; u += 256) {
    int l = u >> 4, n2 = (u & 15) * 2;
    bcs[u] = *(const float2*)&bpc[(size_t)(c * CLEN + l) * 32 + n2];
  }
  float halfA[NSTATE], h[NSTATE];
#pragma unroll
  for (int n = 0; n < NSTATE; ++n) {
    halfA[n] = -0.5f * __expf(A_log[d * NSTATE + n]);
    h[n] = Hinit[(size_t)c * (DDIM * NSTATE) + n * DDIM + d];
  }
  const float dsk = Dskip[d];
  __syncthreads();
  const _Float16* sdr = sdh + (size_t)c * CLEN * DDIM + d;
  const _Float16* xr = xnh + (size_t)c * CLEN * DDIM + d;
  float* yr = y + (size_t)c * CLEN * DDIM + d;
#pragma unroll 2
  for (int i = 0; i < CLEN; ++i) {
    float sdv = (float)sdr[(size_t)i * DDIM];
    float xv = (float)xr[(size_t)i * DDIM];
    float dsq = sdv * sdv;
    float sdx = sdv * xv;
    float acc = dsk * xv;
#pragma unroll
    for (int n = 0; n < NSTATE; ++n) {
      float2 bc = bcs[i * NSTATE + n];
      float hd = dsq * halfA[n];
      float di = __builtin_amdgcn_rcpf(1.0f - hd);
      float ab = fmaf(hd, di, di);
      h[n] = fmaf(ab, h[n], sdx * bc.x * di);
      acc = fmaf(bc.y, h[n], acc);
    }
    yr[(size_t)i * DDIM] = acc;
  }
}

// ---------------- launch ----------------
extern "C" void kernel_launch(void* const* d_in, const int* in_sizes, int n_in,
                              void* d_out, int out_size, void* d_ws, size_t ws_size,
                              hipStream_t stream) {
  const float* x       = (const float*)d_in[0];
  const float* A_log   = (const float*)d_in[1];
  const float* W_delta = (const float*)d_in[2];
  const float* b_delta = (const float*)d_in[3];
  const float* W_B     = (const float*)d_in[4];
  const float* W_C     = (const float*)d_in[5];
  const float* D_skip  = (const float*)d_in[6];
  const float* norm_w  = (const float*)d_in[7];
  float* y = (float*)d_out;

  char* ws = (char*)d_ws;
  const size_t MB = 1024 * 1024;
  _Float16* xnh = (_Float16*)(ws);              //  8 MB xn f16
  _Float16* Wt  = (_Float16*)(ws + 8 * MB);     //  2 MB W_delta^T f16
  _Float16* BCe = (_Float16*)(ws + 10 * MB);    // 64 KB packed W_B/W_C f16 (32 x 1024)
  _Float16* sdh = (_Float16*)(ws + 11 * MB);    //  8 MB sqrt(delta) f16
  float*    bpc = (float*)(ws + 19 * MB);       // 512 KB BC accumulator [4096][32]
  float2*   Ph  = (float2*)(ws + 20 * MB);      // 16 MB {prodA, h_end}
  float*    Hin = (float*)(ws + 36 * MB);       //  8 MB chunk-entry states
  (void)ws_size; (void)in_sizes; (void)n_in; (void)out_size;

  hipLaunchKernelGGL(k_prep_norm, dim3(4368), dim3(256), 0, stream,
                     x, norm_w, W_delta, W_B, W_C, xnh, Wt, BCe, bpc);
  hipLaunchKernelGGL(k_gemm64, dim3(512), dim3(256), 0, stream,
                     xnh, Wt, BCe, b_delta, sdh, bpc);
  hipLaunchKernelGGL(k_scan1, dim3(4, NCHUNK), dim3(256), 0, stream,
                     sdh, xnh, bpc, A_log, Ph);
  hipLaunchKernelGGL(k_comb, dim3(256), dim3(64), 0, stream, Ph, Hin);
  hipLaunchKernelGGL(k_scan2, dim3(4, NCHUNK), dim3(256), 0, stream,
                     sdh, xnh, bpc, A_log, Hin, D_skip, y);
}